// Round 8
// baseline (181.970 us; speedup 1.0000x reference)
//
#include <hip/hip_runtime.h>
#include <hip/hip_bf16.h>

typedef unsigned short u16;
typedef short bf16x8 __attribute__((ext_vector_type(8)));
typedef float f32x4 __attribute__((ext_vector_type(4)));

#define S_LEN 2048
#define DQ 512
#define NBATCH 4

__device__ __forceinline__ u16 f2bf(float f) {
    __hip_bfloat16 h = __float2bfloat16(f);
    return *reinterpret_cast<u16*>(&h);
}
__device__ __forceinline__ float bf2f(u16 u) {
    unsigned v = ((unsigned)u) << 16;
    union { unsigned u; float f; } c; c.u = v; return c.f;
}

__device__ __forceinline__ void async16(const u16* g, u16* l) {
    __builtin_amdgcn_global_load_lds(
        (__attribute__((address_space(1))) void*)g,
        (__attribute__((address_space(3))) void*)l, 16, 0, 0);
}

// XCD-chunked bijective swizzle (T1): hardware assigns dispatch id d -> XCD d%8.
__device__ __forceinline__ int xcd_swz(int bid, int chunk) {
    return (bid & 7) * chunk + (bid >> 3);
}

// -------- fp32 -> bf16 convert: x + Wq + Wk + Wv; tail blocks zero the sums buffer --------
__global__ __launch_bounds__(256) void k_cvt_all(const float* __restrict__ x,
                                                 const float* __restrict__ wq,
                                                 const float* __restrict__ wk,
                                                 const float* __restrict__ wv,
                                                 u16* __restrict__ xb, u16* __restrict__ wb,
                                                 float* __restrict__ sums) {
    int bid = blockIdx.x;
    if (bid >= 4864) {  // 8 blocks zero sums[8192]
        int i = (bid - 4864) * 256 + threadIdx.x;
        *(f32x4*)(sums + (size_t)i * 4) = (f32x4)0.0f;
        return;
    }
    const float* src;
    u16* dst;
    int i;
    if (bid < 4096)      { src = x;  dst = xb;          i = bid * 256 + threadIdx.x; }
    else if (bid < 4352) { src = wq; dst = wb;          i = (bid - 4096) * 256 + threadIdx.x; }
    else if (bid < 4608) { src = wk; dst = wb + 262144; i = (bid - 4352) * 256 + threadIdx.x; }
    else                 { src = wv; dst = wb + 524288; i = (bid - 4608) * 256 + threadIdx.x; }
    f32x4 v = *(const f32x4*)(src + (size_t)i * 4);
    ushort4 o;
    o.x = f2bf(v.x); o.y = f2bf(v.y); o.z = f2bf(v.z); o.w = f2bf(v.w);
    *(ushort4*)(dst + (size_t)i * 4) = o;
}

// ========== 256x256 GEMM core: BK=32, TRIPLE-buffered LDS, counted vmcnt ==========
// Per-matrix buffer: [256 rows][32 cols] bf16 = 16 KB = 64 B/row = 4 chunks of 16 B.
// XOR swizzle: physical chunk = logical chunk ^ (row & 3); applied on the global
// SOURCE (stage) and the ds_read address (rule 21 both-sides, LDS dest linear).
// Stage per tile = 2 loads/thread (A) + 2 (B) = 4 -> tile-end s_waitcnt vmcnt(4)
// guarantees tile kt+1's stages while kt+2's 4 loads stay in flight (never drains
// to 0 in the main loop -- T4; same invariant as k_pv since round 6).
__device__ __forceinline__ void stage32(const u16* __restrict__ G, u16* buf,
                                        int kcol, int tid) {
#pragma unroll
    for (int q = 0; q < 2; ++q) {
        int c   = q * 512 + tid;          // 16B chunk id 0..1023
        int r   = c >> 2;                 // row 0..255
        int p   = c & 3;                  // physical chunk within row
        int lch = p ^ (r & 3);            // logical (global) chunk
        async16(G + (size_t)r * DQ + kcol + lch * 8,
                buf + c * 8);             // linear dest: wave-uniform base + lane*16B
    }
}

// A,B: row-major panels [256][512] (row stride DQ). C = A * B^T on 256x256 tile.
// acc[8][4]: wave (wr=w>>2, wc=w&3) owns rows wr*128..+127, cols wc*64..+63.
__device__ __forceinline__ void gemm256(const u16* __restrict__ A, const u16* __restrict__ B,
                                        u16* ldsA, u16* ldsB, f32x4 acc[8][4], int tid) {
    const int lane = tid & 63;
    const int w    = tid >> 6;
    const int wr   = w >> 2;
    const int wc   = w & 3;
    const int l16  = lane & 15;
    const int quad = lane >> 4;
    const int pch  = (quad ^ (l16 & 3)) * 8;          // swizzled k-chunk (u16 offset)
    const int a0   = (wr * 128 + l16) * 32 + pch;     // +i*512 per m-frag
    const int b0   = (wc * 64 + l16) * 32 + pch;      // +j*512 per n-frag

    // prologue: stage tiles 0,1 (8 loads/thread); guarantee tile 0, keep tile 1 in flight
    stage32(A, ldsA, 0, tid);
    stage32(B, ldsB, 0, tid);
    stage32(A, ldsA + 8192, 32, tid);
    stage32(B, ldsB + 8192, 32, tid);
    asm volatile("s_waitcnt vmcnt(4)" ::: "memory");
    __builtin_amdgcn_s_barrier();
    __builtin_amdgcn_sched_barrier(0);

    int rb = 0;                            // read-buffer index = kt % 3
    for (int kt = 0; kt < 16; ++kt) {
        const u16* rdA = ldsA + rb * 8192;
        const u16* rdB = ldsB + rb * 8192;

        if (kt < 14) {
            int wbi = rb >= 1 ? rb - 1 : 2;   // (kt+2) % 3
            const int kc = (kt + 2) * 32;
            stage32(A, ldsA + wbi * 8192, kc, tid);
            stage32(B, ldsB + wbi * 8192, kc, tid);
        }

        bf16x8 af[4], bf[4];
        // ---- G0: read A m0-3 + B n0-1; MFMA m0-3 x n0-1 ----
#pragma unroll
        for (int i = 0; i < 4; ++i) af[i] = *(const bf16x8*)(rdA + a0 + i * 512);
#pragma unroll
        for (int j = 0; j < 2; ++j) bf[j] = *(const bf16x8*)(rdB + b0 + j * 512);
        __builtin_amdgcn_s_setprio(1);
#pragma unroll
        for (int i = 0; i < 4; ++i)
#pragma unroll
            for (int j = 0; j < 2; ++j)
                acc[i][j] = __builtin_amdgcn_mfma_f32_16x16x32_bf16(af[i], bf[j], acc[i][j], 0, 0, 0);
        __builtin_amdgcn_s_setprio(0);

        // ---- G1: read B n2-3; MFMA m0-3 x n2-3 ----
#pragma unroll
        for (int j = 0; j < 2; ++j) bf[2 + j] = *(const bf16x8*)(rdB + b0 + (2 + j) * 512);
        __builtin_amdgcn_s_setprio(1);
#pragma unroll
        for (int i = 0; i < 4; ++i)
#pragma unroll
            for (int j = 0; j < 2; ++j)
                acc[i][2 + j] = __builtin_amdgcn_mfma_f32_16x16x32_bf16(af[i], bf[2 + j], acc[i][2 + j], 0, 0, 0);
        __builtin_amdgcn_s_setprio(0);

        // ---- G2: read A m4-7; MFMA m4-7 x n2-3 ----
#pragma unroll
        for (int i = 0; i < 4; ++i) af[i] = *(const bf16x8*)(rdA + a0 + (4 + i) * 512);
        __builtin_amdgcn_s_setprio(1);
#pragma unroll
        for (int i = 0; i < 4; ++i)
#pragma unroll
            for (int j = 0; j < 2; ++j)
                acc[4 + i][2 + j] = __builtin_amdgcn_mfma_f32_16x16x32_bf16(af[i], bf[2 + j], acc[4 + i][2 + j], 0, 0, 0);
        __builtin_amdgcn_s_setprio(0);

        // ---- G3: MFMA m4-7 x n0-1 ----
        __builtin_amdgcn_s_setprio(1);
#pragma unroll
        for (int i = 0; i < 4; ++i)
#pragma unroll
            for (int j = 0; j < 2; ++j)
                acc[4 + i][j] = __builtin_amdgcn_mfma_f32_16x16x32_bf16(af[i], bf[j], acc[4 + i][j], 0, 0, 0);
        __builtin_amdgcn_s_setprio(0);

        if (kt < 15) {
            if (kt < 14) asm volatile("s_waitcnt vmcnt(4)" ::: "memory");
            else         asm volatile("s_waitcnt vmcnt(0)" ::: "memory");
            __builtin_amdgcn_s_barrier();
            __builtin_amdgcn_sched_barrier(0);
        }
        rb = (rb == 2) ? 0 : rb + 1;
    }
}

// -------- projection: z in {Q,K,V}; 256x256 tiles; nwg = 192 = (z=3)x(by=32)x(bx=2) --------
__global__ __launch_bounds__(512, 2) void k_proj(const u16* __restrict__ xb, const u16* __restrict__ Wb,
                                                 const float* __restrict__ bq, const float* __restrict__ bk,
                                                 const float* __restrict__ bv, u16* __restrict__ out,
                                                 u16* __restrict__ VT) {
    __shared__ __align__(16) u16 lds[49152];   // 96 KiB: A 3x8192 | B 3x8192
    const int l  = xcd_swz(blockIdx.x, 24);
    const int bx = l & 1;
    const int by = (l >> 1) & 31;
    const int z  = l >> 6;
    const int m0 = by * 256, n0 = bx * 256;
    const u16* A = xb + (size_t)m0 * DQ;
    const u16* B = Wb + (size_t)z * DQ * DQ + (size_t)n0 * DQ;
    const float* bias = (z == 0) ? bq : (z == 1) ? bk : bv;

    f32x4 acc[8][4];
#pragma unroll
    for (int i = 0; i < 8; ++i)
#pragma unroll
        for (int j = 0; j < 4; ++j) acc[i][j] = (f32x4)0.0f;

    const int tid = threadIdx.x;
    gemm256(A, B, lds, lds + 24576, acc, tid);

    const int lane = tid & 63, w = tid >> 6;
    const int wr = w >> 2, wc = w & 3;
    const int l16 = lane & 15, quad = lane >> 4;

    if (z < 2) {
        u16* outz = out + (size_t)z * 8192 * DQ;
#pragma unroll
        for (int j = 0; j < 4; ++j) {
            int gn = n0 + wc * 64 + j * 16 + l16;
            float bv_ = bias[gn];
#pragma unroll
            for (int i = 0; i < 8; ++i)
#pragma unroll
                for (int r = 0; r < 4; ++r) {
                    int gm = m0 + wr * 128 + i * 16 + quad * 4 + r;
                    outz[(size_t)gm * DQ + gn] = f2bf(acc[i][j][r] + bv_);
                }
        }
    } else {
        const int bb_ = m0 >> 11;
        u16* VTb_ = VT + (size_t)bb_ * DQ * S_LEN;
#pragma unroll
        for (int j = 0; j < 4; ++j) {
            int gn = n0 + wc * 64 + j * 16 + l16;
            float bv_ = bias[gn];
#pragma unroll
            for (int i = 0; i < 8; ++i) {
                int t0 = (m0 & 2047) + wr * 128 + i * 16 + quad * 4;
                ushort4 o;
                o.x = f2bf(acc[i][j][0] + bv_);
                o.y = f2bf(acc[i][j][1] + bv_);
                o.z = f2bf(acc[i][j][2] + bv_);
                o.w = f2bf(acc[i][j][3] + bv_);
                *(ushort4*)(VTb_ + (size_t)gn * S_LEN + t0) = o;
            }
        }
    }
}

// -------- scores: 256x256 tiles; e=exp(QK^T*scale)->bf16 Pb + atomic row sums --------
__global__ __launch_bounds__(512, 2) void k_scores(const u16* __restrict__ Qb, const u16* __restrict__ Kb,
                                                   u16* __restrict__ Pb, float* __restrict__ sums) {
    __shared__ __align__(16) u16 lds[49152];
    const int l  = xcd_swz(blockIdx.x, 32);
    const int bx = l & 7;
    const int by = (l >> 3) & 7;
    const int b  = l >> 6;
    const int m0 = by * 256, n0 = bx * 256;
    const u16* A = Qb + ((size_t)b * S_LEN + m0) * DQ;
    const u16* B = Kb + ((size_t)b * S_LEN + n0) * DQ;

    f32x4 acc[8][4];
#pragma unroll
    for (int i = 0; i < 8; ++i)
#pragma unroll
        for (int j = 0; j < 4; ++j) acc[i][j] = (f32x4)0.0f;

    const int tid = threadIdx.x;
    gemm256(A, B, lds, lds + 24576, acc, tid);

    const float scale = 0.044194173824159216f; // 1/sqrt(512)
    const int lane = tid & 63, w = tid >> 6;
    const int wr = w >> 2, wc = w & 3;
    const int l16 = lane & 15, quad = lane >> 4;
    u16* prow = Pb + (size_t)(b * S_LEN + m0) * S_LEN;

    float psum[8][4];
#pragma unroll
    for (int i = 0; i < 8; ++i)
#pragma unroll
        for (int r = 0; r < 4; ++r) psum[i][r] = 0.0f;

#pragma unroll
    for (int i = 0; i < 8; ++i)
#pragma unroll
        for (int j = 0; j < 4; ++j)
#pragma unroll
            for (int r = 0; r < 4; ++r) {
                int gm = wr * 128 + i * 16 + quad * 4 + r;
                int gn = n0 + wc * 64 + j * 16 + l16;
                float e = __expf(acc[i][j][r] * scale);
                u16 pbv = f2bf(e);
                prow[(size_t)gm * S_LEN + gn] = pbv;
                psum[i][r] += bf2f(pbv);
            }

    float* sums_row = sums + b * S_LEN + m0 + wr * 128;
#pragma unroll
    for (int i = 0; i < 8; ++i)
#pragma unroll
        for (int r = 0; r < 4; ++r) {
            float v = psum[i][r];
            v += __shfl_xor(v, 1);
            v += __shfl_xor(v, 2);
            v += __shfl_xor(v, 4);
            v += __shfl_xor(v, 8);
            if (l16 == 0) atomicAdd(&sums_row[i * 16 + quad * 4 + r], v);
        }
}

// ======== k_pv: 128x128 tile, 8 waves, BK=64, triple-buffered, counted vmcnt ========
// (unchanged from round 7: probs pass interleaved into the K-loop)
__device__ __forceinline__ void stage_pv(const u16* __restrict__ G, u16* buf,
                                         int kcol, int h, int tid) {
    int c   = tid;                 // 16B chunk 0..511 within half (64 rows x 8 chunks)
    int r   = c >> 3;              // row 0..63
    int p   = c & 7;               // physical chunk
    int lch = p ^ (r & 7);         // logical chunk (pre-swizzled source)
    async16(G + (size_t)(h * 64 + r) * S_LEN + kcol + lch * 8,
            buf + h * 4096 + c * 8);
}

__global__ __launch_bounds__(512, 2) void k_pv(const u16* __restrict__ Pb, const u16* __restrict__ VT,
                                               const float* __restrict__ sums,
                                               float* __restrict__ probs,
                                               float* __restrict__ wout) {
    __shared__ __align__(16) u16 lds[49408];   // A 3x8192 | B 3x8192 | inv 128 f32
    u16* ldsA = lds;
    u16* ldsB = lds + 24576;
    float* ldsInv = (float*)(lds + 49152);
    const int l  = xcd_swz(blockIdx.x, 32);
    const int bx = l & 3;
    const int by = (l >> 2) & 15;
    const int b  = l >> 6;
    const int m0 = by * 128, n0 = bx * 128;
    const u16* A = Pb + (size_t)(b * S_LEN + m0) * S_LEN;
    const u16* B = VT + (size_t)b * DQ * S_LEN + (size_t)n0 * S_LEN;
    const u16* Psl = Pb + (size_t)(b * S_LEN + m0) * S_LEN + bx * 512;
    float* Pro = probs + ((size_t)b * S_LEN + m0) * S_LEN + bx * 512;

    const int tid  = threadIdx.x;
    const int lane = tid & 63;
    const int w    = tid >> 6;
    const int wr   = w >> 2;       // 0..1 -> rows wr*64..+63
    const int wc   = w & 3;        // 0..3 -> cols wc*32..+31
    const int l16  = lane & 15;
    const int quad = lane >> 4;
    const int p0   = quad ^ (l16 & 7);
    const int a0   = (wr * 64 + l16) * 64 + p0 * 8;
    const int a1   = (wr * 64 + l16) * 64 + (p0 ^ 4) * 8;
    const int b0   = (wc * 32 + l16) * 64 + p0 * 8;
    const int b1   = (wc * 32 + l16) * 64 + (p0 ^ 4) * 8;

    f32x4 acc[4][2];
#pragma unroll
    for (int i = 0; i < 4; ++i)
#pragma unroll
        for (int j = 0; j < 2; ++j) acc[i][j] = (f32x4)0.0f;

    float sv = 1.0f;
    if (tid < 128) sv = sums[b * S_LEN + m0 + tid];
    stage_pv(A, ldsA, 0, 0, tid);          stage_pv(A, ldsA, 0, 1, tid);
    stage_pv(B, ldsB, 0, 0, tid);          stage_pv(B, ldsB, 0, 1, tid);
    stage_pv(A, ldsA + 8192, 64, 0, tid);  stage_pv(A, ldsA + 8192, 64, 1, tid);
    stage_pv(B, ldsB + 8192, 64, 0, tid);  stage_pv(B, ldsB + 8192, 64, 1, tid);
    if (tid < 128) ldsInv[tid] = 1.0f / sv;
    asm volatile("s_waitcnt vmcnt(4) lgkmcnt(0)" ::: "memory");
    __builtin_amdgcn_s_barrier();
    __builtin_amdgcn_sched_barrier(0);

    int rb = 0;                            // read-buffer index = kt % 3
    for (int kt = 0; kt < 32; ++kt) {
        const u16* rdA = ldsA + rb * 8192;
        const u16* rdB = ldsB + rb * 8192;

        const bool do_probs = (kt & 1) == 0;
        bf16x8 pvv;
        float pinv = 0.0f;
        float* pdst = nullptr;
        if (do_probs) {
            int idx = (kt >> 1) * 512 + tid;   // chunk-iter 0..15
            int r  = idx >> 6;                 // row 0..127
            int cc = (idx & 63) << 3;          // col 0..511 step 8
            pvv  = *(const bf16x8*)(Psl + (size_t)r * S_LEN + cc);
            pinv = ldsInv[r];
            pdst = Pro + (size_t)r * S_LEN + cc;
        }

        if (kt < 30) {
            int wbi = rb >= 1 ? rb - 1 : 2;   // (kt+2) % 3
            u16* wA = ldsA + wbi * 8192;
            u16* wB = ldsB + wbi * 8192;
            const int kc = (kt + 2) * 64;
            stage_pv(A, wA, kc, 0, tid);
            stage_pv(A, wA, kc, 1, tid);
            stage_pv(B, wB, kc, 0, tid);
            stage_pv(B, wB, kc, 1, tid);
        }

        bf16x8 a[4][2], bbf[2];
#pragma unroll
        for (int i = 0; i < 4; ++i) {
            a[i][0] = *(const bf16x8*)(rdA + a0 + i * 1024);
            a[i][1] = *(const bf16x8*)(rdA + a1 + i * 1024);
        }
        bbf[0] = *(const bf16x8*)(rdB + b0);
        bbf[1] = *(const bf16x8*)(rdB + b1);
        __builtin_amdgcn_s_setprio(1);
#pragma unroll
        for (int i = 0; i < 4; ++i) {
            acc[i][0] = __builtin_amdgcn_mfma_f32_16x16x32_bf16(a[i][0], bbf[0], acc[i][0], 0, 0, 0);
            acc[i][0] = __builtin_amdgcn_mfma_f32_16x16x32_bf16(a[i][1], bbf[1], acc[i][0], 0, 0, 0);
        }
        __builtin_amdgcn_s_setprio(0);

        bbf[0] = *(const bf16x8*)(rdB + b0 + 1024);
        bbf[1] = *(const bf16x8*)(rdB + b1 + 1024);
        __builtin_amdgcn_s_setprio(1);
#pragma unroll
        for (int i = 0; i < 4; ++i) {
            acc[i][1] = __builtin_amdgcn_mfma_f32_16x16x32_bf16(a[i][0], bbf[0], acc[i][1], 0, 0, 0);
            acc[i][1] = __builtin_amdgcn_mfma_f32_16x16x32_bf16(a[i][1], bbf[1], acc[i][1], 0, 0, 0);
        }
        __builtin_amdgcn_s_setprio(0);

        if (do_probs) {
            f32x4 o0, o1;
            o0.x = bf2f((u16)pvv[0]) * pinv;
            o0.y = bf2f((u16)pvv[1]) * pinv;
            o0.z = bf2f((u16)pvv[2]) * pinv;
            o0.w = bf2f((u16)pvv[3]) * pinv;
            o1.x = bf2f((u16)pvv[4]) * pinv;
            o1.y = bf2f((u16)pvv[5]) * pinv;
            o1.z = bf2f((u16)pvv[6]) * pinv;
            o1.w = bf2f((u16)pvv[7]) * pinv;
            *(f32x4*)(pdst) = o0;
            *(f32x4*)(pdst + 4) = o1;
        }

        if (kt < 31) {
            if (kt < 30) asm volatile("s_waitcnt vmcnt(6)" ::: "memory");
            else         asm volatile("s_waitcnt vmcnt(2)" ::: "memory");
            __builtin_amdgcn_s_barrier();
            __builtin_amdgcn_sched_barrier(0);
        }
        rb = (rb == 2) ? 0 : rb + 1;
    }

    float* outb = wout + (size_t)b * S_LEN * DQ;
#pragma unroll
    for (int i = 0; i < 4; ++i) {
#pragma unroll
        for (int r = 0; r < 4; ++r) {
            int lm = wr * 64 + i * 16 + quad * 4 + r;
            float inv = ldsInv[lm];
#pragma unroll
            for (int j = 0; j < 2; ++j) {
                int gn = n0 + wc * 32 + j * 16 + l16;
                outb[(size_t)(m0 + lm) * DQ + gn] = acc[i][j][r] * inv;
            }
        }
    }
}

extern "C" void kernel_launch(void* const* d_in, const int* in_sizes, int n_in,
                              void* d_out, int out_size, void* d_ws, size_t ws_size,
                              hipStream_t stream) {
    const float* x  = (const float*)d_in[0];
    const float* Wq = (const float*)d_in[1];
    const float* bq = (const float*)d_in[2];
    const float* Wk = (const float*)d_in[3];
    const float* bk = (const float*)d_in[4];
    const float* Wv = (const float*)d_in[5];
    const float* bv = (const float*)d_in[6];

    char* ws = (char*)d_ws;
    u16* xb  = (u16*)(ws);                 // x bf16        [8192][512]   8.39 MB
    u16* Wb  = (u16*)(ws + 8388608);       // Wq,Wk,Wv bf16 3x[512][512]  1.57 MB
    u16* Qb  = (u16*)(ws + 9961472);       // Q bf16        [8192][512]
    u16* Kb  = (u16*)(ws + 18350080);      // K bf16        [8192][512]
    u16* VTb = (u16*)(ws + 35127296);      // V^T bf16      [4][512][2048]
    u16* Pb  = (u16*)(ws + 43515904);      // e bf16 (unnormalized) [8192][2048]  33.6 MB
    float* sums = (float*)(ws + 77070336); // [8192] fp32 row sums (atomic)
    float* probs = (float*)d_out;                        // [4][2048][2048]
    float* wout  = (float*)d_out + 16777216;             // [4][2048][512]

    k_cvt_all<<<4872, 256, 0, stream>>>(x, Wq, Wk, Wv, xb, Wb, sums);
    k_proj<<<192, 512, 0, stream>>>(xb, Wb, bq, bk, bv, Qb, VTb);
    k_scores<<<256, 512, 0, stream>>>(Qb, Kb, Pb, sums);
    k_pv<<<256, 512, 0, stream>>>(Pb, VTb, sums, probs, wout);
}

// Round 9
// 173.587 us; speedup vs baseline: 1.0483x; 1.0483x over previous
//
#include <hip/hip_runtime.h>
#include <hip/hip_bf16.h>

typedef unsigned short u16;
typedef short bf16x8 __attribute__((ext_vector_type(8)));
typedef float f32x4 __attribute__((ext_vector_type(4)));

#define S_LEN 2048
#define DQ 512
#define NBATCH 4

__device__ __forceinline__ u16 f2bf(float f) {
    __hip_bfloat16 h = __float2bfloat16(f);
    return *reinterpret_cast<u16*>(&h);
}
__device__ __forceinline__ float bf2f(u16 u) {
    unsigned v = ((unsigned)u) << 16;
    union { unsigned u; float f; } c; c.u = v; return c.f;
}

__device__ __forceinline__ void async16(const u16* g, u16* l) {
    __builtin_amdgcn_global_load_lds(
        (__attribute__((address_space(1))) void*)g,
        (__attribute__((address_space(3))) void*)l, 16, 0, 0);
}

// XCD-chunked bijective swizzle (T1): hardware assigns dispatch id d -> XCD d%8.
__device__ __forceinline__ int xcd_swz(int bid, int chunk) {
    return (bid & 7) * chunk + (bid >> 3);
}

// SWAP=1 computes mfma(B,A) -> transposed C fragment (lane regs run along N).
template<int SWAP>
__device__ __forceinline__ f32x4 mm(bf16x8 af, bf16x8 bf, f32x4 c) {
    if constexpr (SWAP)
        return __builtin_amdgcn_mfma_f32_16x16x32_bf16(bf, af, c, 0, 0, 0);
    else
        return __builtin_amdgcn_mfma_f32_16x16x32_bf16(af, bf, c, 0, 0, 0);
}

// -------- fp32 -> bf16 convert: x + Wq + Wk + Wv; tail blocks zero the sums buffer --------
__global__ __launch_bounds__(256) void k_cvt_all(const float* __restrict__ x,
                                                 const float* __restrict__ wq,
                                                 const float* __restrict__ wk,
                                                 const float* __restrict__ wv,
                                                 u16* __restrict__ xb, u16* __restrict__ wb,
                                                 float* __restrict__ sums) {
    int bid = blockIdx.x;
    if (bid >= 4864) {  // 8 blocks zero sums[8192]
        int i = (bid - 4864) * 256 + threadIdx.x;
        *(f32x4*)(sums + (size_t)i * 4) = (f32x4)0.0f;
        return;
    }
    const float* src;
    u16* dst;
    int i;
    if (bid < 4096)      { src = x;  dst = xb;          i = bid * 256 + threadIdx.x; }
    else if (bid < 4352) { src = wq; dst = wb;          i = (bid - 4096) * 256 + threadIdx.x; }
    else if (bid < 4608) { src = wk; dst = wb + 262144; i = (bid - 4352) * 256 + threadIdx.x; }
    else                 { src = wv; dst = wb + 524288; i = (bid - 4608) * 256 + threadIdx.x; }
    f32x4 v = *(const f32x4*)(src + (size_t)i * 4);
    ushort4 o;
    o.x = f2bf(v.x); o.y = f2bf(v.y); o.z = f2bf(v.z); o.w = f2bf(v.w);
    *(ushort4*)(dst + (size_t)i * 4) = o;
}

// ================= 256x256 double-buffered GEMM core (BK=64, 8 waves) =================
// (R7 core, verified at 177.9 us.) LDS per matrix buffer: [256 rows][64 cols] bf16,
// 128 B/row = 8 chunks of 16 B. XOR swizzle: physical chunk = logical ^ (row & 7),
// applied on the global SOURCE (stage) + swizzled ds_read (rule 21 both-sides).
__device__ __forceinline__ void stage_unit(const u16* __restrict__ G, u16* buf,
                                           int kcol, int h, int tid) {
#pragma unroll
    for (int q = 0; q < 2; ++q) {
        int c   = q * 512 + tid;          // 16B chunk id 0..1023 within half-tile
        int r   = c >> 3;                 // row 0..127 within half
        int p   = c & 7;                  // physical chunk within row
        int lch = p ^ (r & 7);            // logical (global) chunk
        async16(G + (size_t)(h * 128 + r) * DQ + kcol + lch * 8,
                buf + h * 8192 + c * 8);  // linear dest: wave-uniform base + lane*16B
    }
}

// A,B: row-major panels [256][512] (row stride DQ). C = A * B^T on 256x256 tile.
// SWAP=0: acc[i][j] = frag(m=i,n=j), lane regs along M (rows quad*4+r, col l16).
// SWAP=1: acc[i][j] = transposed frag, lane regs along N (cols quad*4+r, row l16).
template<int SWAP>
__device__ __forceinline__ void gemm256(const u16* __restrict__ A, const u16* __restrict__ B,
                                        u16* ldsA, u16* ldsB, f32x4 acc[8][4], int tid) {
    const int lane = tid & 63;
    const int w    = tid >> 6;
    const int wr   = w >> 2;
    const int wc   = w & 3;
    const int l16  = lane & 15;
    const int quad = lane >> 4;
    const int p0   = quad ^ (l16 & 7);
    const int a0   = (wr * 128 + l16) * 64 + p0 * 8;
    const int a1   = (wr * 128 + l16) * 64 + (p0 ^ 4) * 8;
    const int b0   = (wc * 64 + l16) * 64 + p0 * 8;
    const int b1   = (wc * 64 + l16) * 64 + (p0 ^ 4) * 8;

    stage_unit(A, ldsA, 0, 0, tid);
    stage_unit(A, ldsA, 0, 1, tid);
    stage_unit(B, ldsB, 0, 0, tid);
    stage_unit(B, ldsB, 0, 1, tid);
    __syncthreads();

    for (int kt = 0; kt < 8; ++kt) {
        const u16* rdA = ldsA + (kt & 1) * 16384;
        const u16* rdB = ldsB + (kt & 1) * 16384;
        u16* wrA = ldsA + ((kt + 1) & 1) * 16384;
        u16* wrB = ldsB + ((kt + 1) & 1) * 16384;
        const int  kc = (kt + 1) * 64;
        const bool pf = kt < 7;
        bf16x8 a[4][2], bbf[2][2];

        // ---- G0: stage A-half0+half1(kt+1); read A m0-3 + B n0-1; MFMA ----
        if (pf) { stage_unit(A, wrA, kc, 0, tid); stage_unit(A, wrA, kc, 1, tid); }
#pragma unroll
        for (int i = 0; i < 4; ++i) {
            a[i][0] = *(const bf16x8*)(rdA + a0 + i * 1024);
            a[i][1] = *(const bf16x8*)(rdA + a1 + i * 1024);
        }
#pragma unroll
        for (int j = 0; j < 2; ++j) {
            bbf[j][0] = *(const bf16x8*)(rdB + b0 + j * 1024);
            bbf[j][1] = *(const bf16x8*)(rdB + b1 + j * 1024);
        }
        __builtin_amdgcn_s_setprio(1);
#pragma unroll
        for (int i = 0; i < 4; ++i)
#pragma unroll
            for (int j = 0; j < 2; ++j) {
                acc[i][j] = mm<SWAP>(a[i][0], bbf[j][0], acc[i][j]);
                acc[i][j] = mm<SWAP>(a[i][1], bbf[j][1], acc[i][j]);
            }
        __builtin_amdgcn_s_setprio(0);

        // ---- G1: stage B-half0+half1(kt+1); read B n2-3; MFMA m0-3 x n2-3 ----
        if (pf) { stage_unit(B, wrB, kc, 0, tid); stage_unit(B, wrB, kc, 1, tid); }
#pragma unroll
        for (int j = 0; j < 2; ++j) {
            bbf[j][0] = *(const bf16x8*)(rdB + b0 + (2 + j) * 1024);
            bbf[j][1] = *(const bf16x8*)(rdB + b1 + (2 + j) * 1024);
        }
        __builtin_amdgcn_s_setprio(1);
#pragma unroll
        for (int i = 0; i < 4; ++i)
#pragma unroll
            for (int j = 0; j < 2; ++j) {
                acc[i][2 + j] = mm<SWAP>(a[i][0], bbf[j][0], acc[i][2 + j]);
                acc[i][2 + j] = mm<SWAP>(a[i][1], bbf[j][1], acc[i][2 + j]);
            }
        __builtin_amdgcn_s_setprio(0);

        // ---- G2: read A m4-7; MFMA m4-7 x n2-3 ----
#pragma unroll
        for (int i = 0; i < 4; ++i) {
            a[i][0] = *(const bf16x8*)(rdA + a0 + (4 + i) * 1024);
            a[i][1] = *(const bf16x8*)(rdA + a1 + (4 + i) * 1024);
        }
        __builtin_amdgcn_s_setprio(1);
#pragma unroll
        for (int i = 0; i < 4; ++i)
#pragma unroll
            for (int j = 0; j < 2; ++j) {
                acc[4 + i][2 + j] = mm<SWAP>(a[i][0], bbf[j][0], acc[4 + i][2 + j]);
                acc[4 + i][2 + j] = mm<SWAP>(a[i][1], bbf[j][1], acc[4 + i][2 + j]);
            }
        __builtin_amdgcn_s_setprio(0);

        // ---- G3: read B n0-1 again; MFMA m4-7 x n0-1 ----
#pragma unroll
        for (int j = 0; j < 2; ++j) {
            bbf[j][0] = *(const bf16x8*)(rdB + b0 + j * 1024);
            bbf[j][1] = *(const bf16x8*)(rdB + b1 + j * 1024);
        }
        __builtin_amdgcn_s_setprio(1);
#pragma unroll
        for (int i = 0; i < 4; ++i)
#pragma unroll
            for (int j = 0; j < 2; ++j) {
                acc[4 + i][j] = mm<SWAP>(a[i][0], bbf[j][0], acc[4 + i][j]);
                acc[4 + i][j] = mm<SWAP>(a[i][1], bbf[j][1], acc[4 + i][j]);
            }
        __builtin_amdgcn_s_setprio(0);

        __syncthreads();
    }
}

// -------- projection: z in {Q,K,V}; 256x256 tiles; nwg = 192 = (z=3)x(by=32)x(bx=2) --------
__global__ __launch_bounds__(512, 2) void k_proj(const u16* __restrict__ xb, const u16* __restrict__ Wb,
                                                 const float* __restrict__ bq, const float* __restrict__ bk,
                                                 const float* __restrict__ bv, u16* __restrict__ out,
                                                 u16* __restrict__ VT) {
    __shared__ __align__(16) u16 lds[65536];   // 128 KiB: A 2x16384 | B 2x16384
    const int l  = xcd_swz(blockIdx.x, 24);
    const int bx = l & 1;
    const int by = (l >> 1) & 31;
    const int z  = l >> 6;
    const int m0 = by * 256, n0 = bx * 256;
    const u16* A = xb + (size_t)m0 * DQ;
    const u16* B = Wb + (size_t)z * DQ * DQ + (size_t)n0 * DQ;
    const float* bias = (z == 0) ? bq : (z == 1) ? bk : bv;

    f32x4 acc[8][4];
#pragma unroll
    for (int i = 0; i < 8; ++i)
#pragma unroll
        for (int j = 0; j < 4; ++j) acc[i][j] = (f32x4)0.0f;

    const int tid = threadIdx.x;
    gemm256<0>(A, B, lds, lds + 32768, acc, tid);

    const int lane = tid & 63, w = tid >> 6;
    const int wr = w >> 2, wc = w & 3;
    const int l16 = lane & 15, quad = lane >> 4;

    if (z < 2) {
        u16* outz = out + (size_t)z * 8192 * DQ;
#pragma unroll
        for (int j = 0; j < 4; ++j) {
            int gn = n0 + wc * 64 + j * 16 + l16;
            float bv_ = bias[gn];
#pragma unroll
            for (int i = 0; i < 8; ++i)
#pragma unroll
                for (int r = 0; r < 4; ++r) {
                    int gm = m0 + wr * 128 + i * 16 + quad * 4 + r;
                    outz[(size_t)gm * DQ + gn] = f2bf(acc[i][j][r] + bv_);
                }
        }
    } else {
        const int bb_ = m0 >> 11;
        u16* VTb_ = VT + (size_t)bb_ * DQ * S_LEN;
#pragma unroll
        for (int j = 0; j < 4; ++j) {
            int gn = n0 + wc * 64 + j * 16 + l16;
            float bv_ = bias[gn];
#pragma unroll
            for (int i = 0; i < 8; ++i) {
                int t0 = (m0 & 2047) + wr * 128 + i * 16 + quad * 4;
                ushort4 o;
                o.x = f2bf(acc[i][j][0] + bv_);
                o.y = f2bf(acc[i][j][1] + bv_);
                o.z = f2bf(acc[i][j][2] + bv_);
                o.w = f2bf(acc[i][j][3] + bv_);
                *(ushort4*)(VTb_ + (size_t)gn * S_LEN + t0) = o;
            }
        }
    }
}

// -------- scores: 256x256 tiles, SWAPPED operands -> vectorized Pb stores --------
// acc[i][j] transposed frag: row gm = wr*128+i*16+l16 (fixed/lane), cols gn =
// n0+wc*64+j*16+quad*4+rr (rr consecutive) -> ushort4 stores (32 vs 128 scalar).
// Row-sum: in-lane over j,rr (16 vals) + shfl_xor(16,32) over quads.
__global__ __launch_bounds__(512, 2) void k_scores(const u16* __restrict__ Qb, const u16* __restrict__ Kb,
                                                   u16* __restrict__ Pb, float* __restrict__ sums) {
    __shared__ __align__(16) u16 lds[65536];
    const int l  = xcd_swz(blockIdx.x, 32);
    const int bx = l & 7;
    const int by = (l >> 3) & 7;
    const int b  = l >> 6;
    const int m0 = by * 256, n0 = bx * 256;
    const u16* A = Qb + ((size_t)b * S_LEN + m0) * DQ;
    const u16* B = Kb + ((size_t)b * S_LEN + n0) * DQ;

    f32x4 acc[8][4];
#pragma unroll
    for (int i = 0; i < 8; ++i)
#pragma unroll
        for (int j = 0; j < 4; ++j) acc[i][j] = (f32x4)0.0f;

    const int tid = threadIdx.x;
    gemm256<1>(A, B, lds, lds + 32768, acc, tid);

    const float scale = 0.044194173824159216f; // 1/sqrt(512)
    const int lane = tid & 63, w = tid >> 6;
    const int wr = w >> 2, wc = w & 3;
    const int l16 = lane & 15, quad = lane >> 4;
    u16* prow = Pb + (size_t)(b * S_LEN + m0) * S_LEN;
    float* sums_row = sums + b * S_LEN + m0 + wr * 128;

#pragma unroll
    for (int i = 0; i < 8; ++i) {
        float ps = 0.0f;
        const size_t rowoff = (size_t)(wr * 128 + i * 16 + l16) * S_LEN;
#pragma unroll
        for (int j = 0; j < 4; ++j) {
            ushort4 o;
            o.x = f2bf(__expf(acc[i][j][0] * scale));
            o.y = f2bf(__expf(acc[i][j][1] * scale));
            o.z = f2bf(__expf(acc[i][j][2] * scale));
            o.w = f2bf(__expf(acc[i][j][3] * scale));
            *(ushort4*)(prow + rowoff + n0 + wc * 64 + j * 16 + quad * 4) = o;
            ps += (bf2f(o.x) + bf2f(o.y)) + (bf2f(o.z) + bf2f(o.w));
        }
        ps += __shfl_xor(ps, 16);
        ps += __shfl_xor(ps, 32);
        if (quad == 0) atomicAdd(&sums_row[i * 16 + l16], ps);
    }
}

// ======== k_pv: 128x128 tile, 8 waves, BK=64, triple-buffered, counted vmcnt ========
// (unchanged from round 7: probs pass interleaved into the K-loop)
__device__ __forceinline__ void stage_pv(const u16* __restrict__ G, u16* buf,
                                         int kcol, int h, int tid) {
    int c   = tid;                 // 16B chunk 0..511 within half (64 rows x 8 chunks)
    int r   = c >> 3;              // row 0..63
    int p   = c & 7;               // physical chunk
    int lch = p ^ (r & 7);         // logical chunk (pre-swizzled source)
    async16(G + (size_t)(h * 64 + r) * S_LEN + kcol + lch * 8,
            buf + h * 4096 + c * 8);
}

__global__ __launch_bounds__(512, 2) void k_pv(const u16* __restrict__ Pb, const u16* __restrict__ VT,
                                               const float* __restrict__ sums,
                                               float* __restrict__ probs,
                                               float* __restrict__ wout) {
    __shared__ __align__(16) u16 lds[49408];   // A 3x8192 | B 3x8192 | inv 128 f32
    u16* ldsA = lds;
    u16* ldsB = lds + 24576;
    float* ldsInv = (float*)(lds + 49152);
    const int l  = xcd_swz(blockIdx.x, 32);
    const int bx = l & 3;
    const int by = (l >> 2) & 15;
    const int b  = l >> 6;
    const int m0 = by * 128, n0 = bx * 128;
    const u16* A = Pb + (size_t)(b * S_LEN + m0) * S_LEN;
    const u16* B = VT + (size_t)b * DQ * S_LEN + (size_t)n0 * S_LEN;
    const u16* Psl = Pb + (size_t)(b * S_LEN + m0) * S_LEN + bx * 512;
    float* Pro = probs + ((size_t)b * S_LEN + m0) * S_LEN + bx * 512;

    const int tid  = threadIdx.x;
    const int lane = tid & 63;
    const int w    = tid >> 6;
    const int wr   = w >> 2;       // 0..1 -> rows wr*64..+63
    const int wc   = w & 3;        // 0..3 -> cols wc*32..+31
    const int l16  = lane & 15;
    const int quad = lane >> 4;
    const int p0   = quad ^ (l16 & 7);
    const int a0   = (wr * 64 + l16) * 64 + p0 * 8;
    const int a1   = (wr * 64 + l16) * 64 + (p0 ^ 4) * 8;
    const int b0   = (wc * 32 + l16) * 64 + p0 * 8;
    const int b1   = (wc * 32 + l16) * 64 + (p0 ^ 4) * 8;

    f32x4 acc[4][2];
#pragma unroll
    for (int i = 0; i < 4; ++i)
#pragma unroll
        for (int j = 0; j < 2; ++j) acc[i][j] = (f32x4)0.0f;

    float sv = 1.0f;
    if (tid < 128) sv = sums[b * S_LEN + m0 + tid];
    stage_pv(A, ldsA, 0, 0, tid);          stage_pv(A, ldsA, 0, 1, tid);
    stage_pv(B, ldsB, 0, 0, tid);          stage_pv(B, ldsB, 0, 1, tid);
    stage_pv(A, ldsA + 8192, 64, 0, tid);  stage_pv(A, ldsA + 8192, 64, 1, tid);
    stage_pv(B, ldsB + 8192, 64, 0, tid);  stage_pv(B, ldsB + 8192, 64, 1, tid);
    if (tid < 128) ldsInv[tid] = 1.0f / sv;
    asm volatile("s_waitcnt vmcnt(4) lgkmcnt(0)" ::: "memory");
    __builtin_amdgcn_s_barrier();
    __builtin_amdgcn_sched_barrier(0);

    int rb = 0;                            // read-buffer index = kt % 3
    for (int kt = 0; kt < 32; ++kt) {
        const u16* rdA = ldsA + rb * 8192;
        const u16* rdB = ldsB + rb * 8192;

        const bool do_probs = (kt & 1) == 0;
        bf16x8 pvv;
        float pinv = 0.0f;
        float* pdst = nullptr;
        if (do_probs) {
            int idx = (kt >> 1) * 512 + tid;   // chunk-iter 0..15
            int r  = idx >> 6;                 // row 0..127
            int cc = (idx & 63) << 3;          // col 0..511 step 8
            pvv  = *(const bf16x8*)(Psl + (size_t)r * S_LEN + cc);
            pinv = ldsInv[r];
            pdst = Pro + (size_t)r * S_LEN + cc;
        }

        if (kt < 30) {
            int wbi = rb >= 1 ? rb - 1 : 2;   // (kt+2) % 3
            u16* wA = ldsA + wbi * 8192;
            u16* wB = ldsB + wbi * 8192;
            const int kc = (kt + 2) * 64;
            stage_pv(A, wA, kc, 0, tid);
            stage_pv(A, wA, kc, 1, tid);
            stage_pv(B, wB, kc, 0, tid);
            stage_pv(B, wB, kc, 1, tid);
        }

        bf16x8 a[4][2], bbf[2];
#pragma unroll
        for (int i = 0; i < 4; ++i) {
            a[i][0] = *(const bf16x8*)(rdA + a0 + i * 1024);
            a[i][1] = *(const bf16x8*)(rdA + a1 + i * 1024);
        }
        bbf[0] = *(const bf16x8*)(rdB + b0);
        bbf[1] = *(const bf16x8*)(rdB + b1);
        __builtin_amdgcn_s_setprio(1);
#pragma unroll
        for (int i = 0; i < 4; ++i) {
            acc[i][0] = __builtin_amdgcn_mfma_f32_16x16x32_bf16(a[i][0], bbf[0], acc[i][0], 0, 0, 0);
            acc[i][0] = __builtin_amdgcn_mfma_f32_16x16x32_bf16(a[i][1], bbf[1], acc[i][0], 0, 0, 0);
        }
        __builtin_amdgcn_s_setprio(0);

        bbf[0] = *(const bf16x8*)(rdB + b0 + 1024);
        bbf[1] = *(const bf16x8*)(rdB + b1 + 1024);
        __builtin_amdgcn_s_setprio(1);
#pragma unroll
        for (int i = 0; i < 4; ++i) {
            acc[i][1] = __builtin_amdgcn_mfma_f32_16x16x32_bf16(a[i][0], bbf[0], acc[i][1], 0, 0, 0);
            acc[i][1] = __builtin_amdgcn_mfma_f32_16x16x32_bf16(a[i][1], bbf[1], acc[i][1], 0, 0, 0);
        }
        __builtin_amdgcn_s_setprio(0);

        if (do_probs) {
            f32x4 o0, o1;
            o0.x = bf2f((u16)pvv[0]) * pinv;
            o0.y = bf2f((u16)pvv[1]) * pinv;
            o0.z = bf2f((u16)pvv[2]) * pinv;
            o0.w = bf2f((u16)pvv[3]) * pinv;
            o1.x = bf2f((u16)pvv[4]) * pinv;
            o1.y = bf2f((u16)pvv[5]) * pinv;
            o1.z = bf2f((u16)pvv[6]) * pinv;
            o1.w = bf2f((u16)pvv[7]) * pinv;
            *(f32x4*)(pdst) = o0;
            *(f32x4*)(pdst + 4) = o1;
        }

        if (kt < 31) {
            if (kt < 30) asm volatile("s_waitcnt vmcnt(6)" ::: "memory");
            else         asm volatile("s_waitcnt vmcnt(2)" ::: "memory");
            __builtin_amdgcn_s_barrier();
            __builtin_amdgcn_sched_barrier(0);
        }
        rb = (rb == 2) ? 0 : rb + 1;
    }

    float* outb = wout + (size_t)b * S_LEN * DQ;
#pragma unroll
    for (int i = 0; i < 4; ++i) {
#pragma unroll
        for (int r = 0; r < 4; ++r) {
            int lm = wr * 64 + i * 16 + quad * 4 + r;
            float inv = ldsInv[lm];
#pragma unroll
            for (int j = 0; j < 2; ++j) {
                int gn = n0 + wc * 32 + j * 16 + l16;
                outb[(size_t)(m0 + lm) * DQ + gn] = acc[i][j][r] * inv;
            }
        }
    }
}

extern "C" void kernel_launch(void* const* d_in, const int* in_sizes, int n_in,
                              void* d_out, int out_size, void* d_ws, size_t ws_size,
                              hipStream_t stream) {
    const float* x  = (const float*)d_in[0];
    const float* Wq = (const float*)d_in[1];
    const float* bq = (const float*)d_in[2];
    const float* Wk = (const float*)d_in[3];
    const float* bk = (const float*)d_in[4];
    const float* Wv = (const float*)d_in[5];
    const float* bv = (const float*)d_in[6];

    char* ws = (char*)d_ws;
    u16* xb  = (u16*)(ws);                 // x bf16        [8192][512]   8.39 MB
    u16* Wb  = (u16*)(ws + 8388608);       // Wq,Wk,Wv bf16 3x[512][512]  1.57 MB
    u16* Qb  = (u16*)(ws + 9961472);       // Q bf16        [8192][512]
    u16* Kb  = (u16*)(ws + 18350080);      // K bf16        [8192][512]
    u16* VTb = (u16*)(ws + 35127296);      // V^T bf16      [4][512][2048]
    u16* Pb  = (u16*)(ws + 43515904);      // e bf16 (unnormalized) [8192][2048]  33.6 MB
    float* sums = (float*)(ws + 77070336); // [8192] fp32 row sums (atomic)
    float* probs = (float*)d_out;                        // [4][2048][2048]
    float* wout  = (float*)d_out + 16777216;             // [4][2048][512]

    k_cvt_all<<<4872, 256, 0, stream>>>(x, Wq, Wk, Wv, xb, Wb, sums);
    k_proj<<<192, 512, 0, stream>>>(xb, Wb, bq, bk, bv, Qb, VTb);
    k_scores<<<256, 512, 0, stream>>>(Qb, Kb, Pb, sums);
    k_pv<<<256, 512, 0, stream>>>(Pb, VTb, sums, probs, wout);
}